// Round 1
// baseline (590.872 us; speedup 1.0000x reference)
//
#include <hip/hip_runtime.h>
#include <hip/hip_bf16.h>

#define B_    16384
#define S_    37
#define F_    17
#define OWN_  9
#define H_    256
#define E_    128
#define NOUT_ 23
#define OBS_ROW 646   // 38*17

typedef __bf16 bf16x8 __attribute__((ext_vector_type(8)));
typedef float  f32x4  __attribute__((ext_vector_type(4)));

#define MFMA(a,b,c) __builtin_amdgcn_mfma_f32_16x16x32_bf16(a, b, c, 0, 0, 0)

// ---- workspace layout (bf16 elements) ----
// cat: B x 160 (cols 0..127 summed, 128..136 s_own, 137..159 zero)
#define CAT_STRIDE 160
#define CAT_OFF   0
#define W1T_OFF   (B_ * CAT_STRIDE)          // 2,621,440
#define W2T_OFF   (W1T_OFF + 256*32)
#define W3T_OFF   (W2T_OFF + 256*256)
#define AW1T_OFF  (W3T_OFF + 128*256)
#define AW2T_OFF  (AW1T_OFF + 256*160)
#define AW3T_OFF  (AW2T_OFF + 256*256)
#define VW1T_OFF  (AW3T_OFF + 32*256)
#define VW2T_OFF  (VW1T_OFF + 256*160)
#define VW3T_OFF  (VW2T_OFF + 256*256)
#define PREP_TOTAL (256*32 + 256*256 + 128*256 + 256*160 + 256*256 + 32*256 + 256*160 + 256*256 + 16*256) // 331,776

// Transpose + pad + convert weights to bf16, B-fragment-friendly layout:
// dst[n*Kp + k] = (k < Ks && n < Ns) ? src[k*Ns + n] : 0
__global__ void prep_kernel(const float* __restrict__ sW1, const float* __restrict__ sW2,
                            const float* __restrict__ sW3, const float* __restrict__ aW1,
                            const float* __restrict__ aW2, const float* __restrict__ aW3,
                            const float* __restrict__ vW1, const float* __restrict__ vW2,
                            const float* __restrict__ vW3, __bf16* __restrict__ ws)
{
    int j = blockIdx.x * 256 + threadIdx.x;
    const float* src; __bf16* dst; int Kp, Ks, Ns;
    if (j < 256*32)                 { dst = ws + W1T_OFF;  src = sW1; Kp = 32;  Ks = 17;  Ns = 256; }
    else if ((j -= 256*32)  < 256*256) { dst = ws + W2T_OFF;  src = sW2; Kp = 256; Ks = 256; Ns = 256; }
    else if ((j -= 256*256) < 128*256) { dst = ws + W3T_OFF;  src = sW3; Kp = 256; Ks = 256; Ns = 128; }
    else if ((j -= 128*256) < 256*160) { dst = ws + AW1T_OFF; src = aW1; Kp = 160; Ks = 137; Ns = 256; }
    else if ((j -= 256*160) < 256*256) { dst = ws + AW2T_OFF; src = aW2; Kp = 256; Ks = 256; Ns = 256; }
    else if ((j -= 256*256) < 32*256)  { dst = ws + AW3T_OFF; src = aW3; Kp = 256; Ks = 256; Ns = 23;  }
    else if ((j -= 32*256)  < 256*160) { dst = ws + VW1T_OFF; src = vW1; Kp = 160; Ks = 137; Ns = 256; }
    else if ((j -= 256*160) < 256*256) { dst = ws + VW2T_OFF; src = vW2; Kp = 256; Ks = 256; Ns = 256; }
    else { j -= 256*256;                 dst = ws + VW3T_OFF; src = vW3; Kp = 256; Ks = 256; Ns = 1;   }
    int n = j / Kp, k = j - n * Kp;
    float v = (k < Ks && n < Ns) ? src[k * Ns + n] : 0.f;
    dst[j] = (__bf16)v;
}

// Fused seq MLP + masked sum. One workgroup = 32 batch rows, loops s = 0..36.
// 4 waves: each owns 64 cols of H1/H2 and 32 cols of H3.
__global__ __launch_bounds__(256, 2) void seq_kernel(
    const float* __restrict__ obs,
    const float* __restrict__ sb1, const float* __restrict__ sb2,
    const float* __restrict__ sb3,
    __bf16* __restrict__ ws)
{
    const __bf16* W1t = ws + W1T_OFF;
    const __bf16* W2t = ws + W2T_OFF;
    const __bf16* W3t = ws + W3T_OFF;
    __bf16* cat = ws + CAT_OFF;

    __shared__ __align__(16) __bf16 Xs[32 * 40];    // 32 tokens x K=32 (pad 40)
    __shared__ __align__(16) __bf16 act[32 * 264];  // 32 x 256 (pad 264), H1 then H2
    __shared__ float smask[32];

    const int tid  = threadIdx.x;
    const int wave = tid >> 6;
    const int lane = tid & 63;
    const int q    = lane >> 4;
    const int l16  = lane & 15;
    const int b0   = blockIdx.x * 32;

    const f32x4 z4 = {0.f, 0.f, 0.f, 0.f};

    for (int i = tid; i < 32 * 40; i += 256) Xs[i] = (__bf16)0.f;

    // s_own -> cat[:,128..136], zero cat[:,137..159]
    if (tid < 32) {
        const int b = b0 + tid;
        const float* op = obs + (size_t)b * OBS_ROW;
        __bf16* crow = cat + (size_t)b * CAT_STRIDE + 128;
        #pragma unroll
        for (int jj = 0; jj < OWN_; ++jj) crow[jj] = (__bf16)op[jj];
        #pragma unroll
        for (int jj = OWN_; jj < 32; ++jj) crow[jj] = (__bf16)0.f;
    }

    // hoist W1 B-frags + biases (invariant over s)
    bf16x8 w1f[4];
    float b1v[4], b2v[4], b3v[2];
    #pragma unroll
    for (int nt = 0; nt < 4; ++nt) {
        const int n = wave * 64 + nt * 16 + l16;
        w1f[nt] = *(const bf16x8*)(W1t + n * 32 + q * 8);
        b1v[nt] = sb1[n];
        b2v[nt] = sb2[n];
    }
    #pragma unroll
    for (int nt = 0; nt < 2; ++nt) b3v[nt] = sb3[wave * 32 + nt * 16 + l16];

    f32x4 vsum[2][2];
    #pragma unroll
    for (int nt = 0; nt < 2; ++nt)
        #pragma unroll
        for (int m = 0; m < 2; ++m) vsum[nt][m] = z4;

    for (int s = 0; s < S_; ++s) {
        __syncthreads();  // protect Xs/smask/act from previous iteration readers
        if (tid < 32) {
            const float* row = obs + (size_t)(b0 + tid) * OBS_ROW + (s + 1) * F_;
            float sm = 0.f;
            #pragma unroll
            for (int c = 0; c < F_; ++c) {
                float v = row[c];
                sm += fabsf(v);
                Xs[tid * 40 + c] = (__bf16)v;
            }
            smask[tid] = sm;   // exact fp32 |sum| for mask
        }
        __syncthreads();

        // ---- layer 1: (32,32) x (32,256) ----
        f32x4 h1[4][2];
        {
            bf16x8 af[2];
            #pragma unroll
            for (int m = 0; m < 2; ++m)
                af[m] = *(const bf16x8*)(Xs + (m * 16 + l16) * 40 + q * 8);
            #pragma unroll
            for (int nt = 0; nt < 4; ++nt)
                #pragma unroll
                for (int m = 0; m < 2; ++m)
                    h1[nt][m] = MFMA(af[m], w1f[nt], z4);
        }
        #pragma unroll
        for (int nt = 0; nt < 4; ++nt)
            #pragma unroll
            for (int m = 0; m < 2; ++m)
                #pragma unroll
                for (int r = 0; r < 4; ++r) {
                    float v = h1[nt][m][r] + b1v[nt];
                    v = v > 0.f ? v : 0.f;
                    act[(m * 16 + q * 4 + r) * 264 + wave * 64 + nt * 16 + l16] = (__bf16)v;
                }
        __syncthreads();

        // ---- layer 2: (32,256) x (256,256) ----
        f32x4 h2[4][2];
        #pragma unroll
        for (int nt = 0; nt < 4; ++nt) { h2[nt][0] = z4; h2[nt][1] = z4; }
        #pragma unroll
        for (int k = 0; k < 8; ++k) {
            bf16x8 a0 = *(const bf16x8*)(act + l16 * 264 + k * 32 + q * 8);
            bf16x8 a1 = *(const bf16x8*)(act + (16 + l16) * 264 + k * 32 + q * 8);
            #pragma unroll
            for (int nt = 0; nt < 4; ++nt) {
                bf16x8 bf = *(const bf16x8*)(W2t + (wave * 64 + nt * 16 + l16) * 256 + k * 32 + q * 8);
                h2[nt][0] = MFMA(a0, bf, h2[nt][0]);
                h2[nt][1] = MFMA(a1, bf, h2[nt][1]);
            }
        }
        __syncthreads();  // all waves done reading H1
        #pragma unroll
        for (int nt = 0; nt < 4; ++nt)
            #pragma unroll
            for (int m = 0; m < 2; ++m)
                #pragma unroll
                for (int r = 0; r < 4; ++r) {
                    float v = h2[nt][m][r] + b2v[nt];
                    v = v > 0.f ? v : 0.f;
                    act[(m * 16 + q * 4 + r) * 264 + wave * 64 + nt * 16 + l16] = (__bf16)v;
                }
        __syncthreads();

        // ---- layer 3: (32,256) x (256,128), mask, accumulate sum ----
        f32x4 h3[2][2];
        #pragma unroll
        for (int nt = 0; nt < 2; ++nt) { h3[nt][0] = z4; h3[nt][1] = z4; }
        #pragma unroll
        for (int k = 0; k < 8; ++k) {
            bf16x8 a0 = *(const bf16x8*)(act + l16 * 264 + k * 32 + q * 8);
            bf16x8 a1 = *(const bf16x8*)(act + (16 + l16) * 264 + k * 32 + q * 8);
            #pragma unroll
            for (int nt = 0; nt < 2; ++nt) {
                bf16x8 bf = *(const bf16x8*)(W3t + (wave * 32 + nt * 16 + l16) * 256 + k * 32 + q * 8);
                h3[nt][0] = MFMA(a0, bf, h3[nt][0]);
                h3[nt][1] = MFMA(a1, bf, h3[nt][1]);
            }
        }
        #pragma unroll
        for (int nt = 0; nt < 2; ++nt)
            #pragma unroll
            for (int m = 0; m < 2; ++m)
                #pragma unroll
                for (int r = 0; r < 4; ++r) {
                    float mv = smask[m * 16 + q * 4 + r];
                    float v = h3[nt][m][r] + b3v[nt];
                    v = v > 0.f ? v : 0.f;
                    vsum[nt][m][r] += (mv != 0.f) ? v : 0.f;
                }
    }

    // write pooled sum -> cat[:, 0..127] (bf16)
    #pragma unroll
    for (int nt = 0; nt < 2; ++nt)
        #pragma unroll
        for (int m = 0; m < 2; ++m)
            #pragma unroll
            for (int r = 0; r < 4; ++r) {
                const int row = m * 16 + q * 4 + r;
                const int col = wave * 32 + nt * 16 + l16;
                cat[(size_t)(b0 + row) * CAT_STRIDE + col] = (__bf16)vsum[nt][m][r];
            }
}

// one 256-wide hidden layer from LDS src (bf16) -> LDS dst (bf16, stride 264)
template <int KSTEPS, int SSTR, int WK>
__device__ __forceinline__ void mlp256(const __bf16* src, const __bf16* __restrict__ Wt,
                                       const float* __restrict__ bias, __bf16* dst,
                                       int wave, int q, int l16)
{
    const f32x4 z4 = {0.f, 0.f, 0.f, 0.f};
    f32x4 acc[4][2];
    #pragma unroll
    for (int nt = 0; nt < 4; ++nt) { acc[nt][0] = z4; acc[nt][1] = z4; }
    #pragma unroll
    for (int k = 0; k < KSTEPS; ++k) {
        bf16x8 a0 = *(const bf16x8*)(src + l16 * SSTR + k * 32 + q * 8);
        bf16x8 a1 = *(const bf16x8*)(src + (16 + l16) * SSTR + k * 32 + q * 8);
        #pragma unroll
        for (int nt = 0; nt < 4; ++nt) {
            bf16x8 bf = *(const bf16x8*)(Wt + (wave * 64 + nt * 16 + l16) * WK + k * 32 + q * 8);
            acc[nt][0] = MFMA(a0, bf, acc[nt][0]);
            acc[nt][1] = MFMA(a1, bf, acc[nt][1]);
        }
    }
    #pragma unroll
    for (int nt = 0; nt < 4; ++nt) {
        float bv = bias[wave * 64 + nt * 16 + l16];
        #pragma unroll
        for (int m = 0; m < 2; ++m)
            #pragma unroll
            for (int r = 0; r < 4; ++r) {
                float v = acc[nt][m][r] + bv;
                v = v > 0.f ? v : 0.f;
                dst[(m * 16 + q * 4 + r) * 264 + wave * 64 + nt * 16 + l16] = (__bf16)v;
            }
    }
}

// Actor + value heads. One workgroup = 32 batch rows.
__global__ __launch_bounds__(256, 2) void head_kernel(
    const __bf16* __restrict__ ws,
    const float* __restrict__ ab1, const float* __restrict__ ab2,
    const float* __restrict__ ab3,
    const float* __restrict__ vb1, const float* __restrict__ vb2,
    const float* __restrict__ vb3,
    float* __restrict__ out)
{
    const __bf16* cat  = ws + CAT_OFF;
    const __bf16* aW1t = ws + AW1T_OFF;
    const __bf16* aW2t = ws + AW2T_OFF;
    const __bf16* aW3t = ws + AW3T_OFF;
    const __bf16* vW1t = ws + VW1T_OFF;
    const __bf16* vW2t = ws + VW2T_OFF;
    const __bf16* vW3t = ws + VW3T_OFF;

    __shared__ __align__(16) __bf16 catS[32 * 168];
    __shared__ __align__(16) __bf16 bufA[32 * 264];
    __shared__ __align__(16) __bf16 bufB[32 * 264];

    const int tid  = threadIdx.x;
    const int wave = tid >> 6;
    const int lane = tid & 63;
    const int q    = lane >> 4;
    const int l16  = lane & 15;
    const int b0   = blockIdx.x * 32;
    const f32x4 z4 = {0.f, 0.f, 0.f, 0.f};

    // stage cat tile: 32 rows x 160 bf16 (20 x 16B chunks per row)
    for (int c = tid; c < 640; c += 256) {
        int r = c / 20, cc = c - r * 20;
        *(bf16x8*)(catS + r * 168 + cc * 8) =
            *(const bf16x8*)(cat + (size_t)(b0 + r) * CAT_STRIDE + cc * 8);
    }
    __syncthreads();

    // actor path
    mlp256<5, 168, 160>(catS, aW1t, ab1, bufA, wave, q, l16);
    __syncthreads();
    mlp256<8, 264, 256>(bufA, aW2t, ab2, bufB, wave, q, l16);
    __syncthreads();

    if (wave < 2) {  // logits: N=23 padded to 32; waves 0,1 handle 16 cols each
        f32x4 acc[2] = {z4, z4};
        #pragma unroll
        for (int k = 0; k < 8; ++k) {
            bf16x8 a0 = *(const bf16x8*)(bufB + l16 * 264 + k * 32 + q * 8);
            bf16x8 a1 = *(const bf16x8*)(bufB + (16 + l16) * 264 + k * 32 + q * 8);
            bf16x8 bf = *(const bf16x8*)(aW3t + (wave * 16 + l16) * 256 + k * 32 + q * 8);
            acc[0] = MFMA(a0, bf, acc[0]);
            acc[1] = MFMA(a1, bf, acc[1]);
        }
        const int col = wave * 16 + l16;
        if (col < NOUT_) {
            const float bv = ab3[col];
            #pragma unroll
            for (int m = 0; m < 2; ++m)
                #pragma unroll
                for (int r = 0; r < 4; ++r)
                    out[(size_t)(b0 + m * 16 + q * 4 + r) * NOUT_ + col] = acc[m][r] + bv;
        }
    }

    // value path (bufA free: a2 finished reading it before the barrier above;
    // logits reads of bufB complete before each wave reaches the next barrier)
    mlp256<5, 168, 160>(catS, vW1t, vb1, bufA, wave, q, l16);
    __syncthreads();
    mlp256<8, 264, 256>(bufA, vW2t, vb2, bufB, wave, q, l16);
    __syncthreads();

    if (wave == 0) {  // value: N=1 padded to 16
        f32x4 acc[2] = {z4, z4};
        #pragma unroll
        for (int k = 0; k < 8; ++k) {
            bf16x8 a0 = *(const bf16x8*)(bufB + l16 * 264 + k * 32 + q * 8);
            bf16x8 a1 = *(const bf16x8*)(bufB + (16 + l16) * 264 + k * 32 + q * 8);
            bf16x8 bf = *(const bf16x8*)(vW3t + l16 * 256 + k * 32 + q * 8);
            acc[0] = MFMA(a0, bf, acc[0]);
            acc[1] = MFMA(a1, bf, acc[1]);
        }
        if (l16 == 0) {
            const float bv = vb3[0];
            #pragma unroll
            for (int m = 0; m < 2; ++m)
                #pragma unroll
                for (int r = 0; r < 4; ++r)
                    out[(size_t)B_ * NOUT_ + b0 + m * 16 + q * 4 + r] = acc[m][r] + bv;
        }
    }
}

extern "C" void kernel_launch(void* const* d_in, const int* in_sizes, int n_in,
                              void* d_out, int out_size, void* d_ws, size_t ws_size,
                              hipStream_t stream)
{
    const float* obs = (const float*)d_in[0];
    const float* sW1 = (const float*)d_in[1];
    const float* sb1 = (const float*)d_in[2];
    const float* sW2 = (const float*)d_in[3];
    const float* sb2 = (const float*)d_in[4];
    const float* sW3 = (const float*)d_in[5];
    const float* sb3 = (const float*)d_in[6];
    const float* aW1 = (const float*)d_in[7];
    const float* ab1 = (const float*)d_in[8];
    const float* aW2 = (const float*)d_in[9];
    const float* ab2 = (const float*)d_in[10];
    const float* aW3 = (const float*)d_in[11];
    const float* ab3 = (const float*)d_in[12];
    const float* vW1 = (const float*)d_in[13];
    const float* vb1 = (const float*)d_in[14];
    const float* vW2 = (const float*)d_in[15];
    const float* vb2 = (const float*)d_in[16];
    const float* vW3 = (const float*)d_in[17];
    const float* vb3 = (const float*)d_in[18];

    __bf16* ws = (__bf16*)d_ws;
    float* out = (float*)d_out;

    hipLaunchKernelGGL(prep_kernel, dim3(PREP_TOTAL / 256), dim3(256), 0, stream,
                       sW1, sW2, sW3, aW1, aW2, aW3, vW1, vW2, vW3, ws);
    hipLaunchKernelGGL(seq_kernel, dim3(B_ / 32), dim3(256), 0, stream,
                       obs, sb1, sb2, sb3, ws);
    hipLaunchKernelGGL(head_kernel, dim3(B_ / 32), dim3(256), 0, stream,
                       (const __bf16*)ws, ab1, ab2, ab3, vb1, vb2, vb3, out);
}